// Round 7
// baseline (120.993 us; speedup 1.0000x reference)
//
#include <hip/hip_runtime.h>
#include <math.h>

// FrequencyMaskingLoss — psychoacoustic masking loss (forward only, scalar out).
// R7: rebuilt ONLY from previously-PASSED components along PASSED seams.
//   k0: tables (R2 exact) + counter init
//   k1: R2's k1 STFT body exact; tail = atomicMax(enc) (R3-passed seam)
//   k3: R2's k3 body exact (block-per-frame, 1247 blocks); serial scan uses
//       readlane regs (R3-passed mechanism, identical f32 compare semantics,
//       NO qmax while-loops — they were R3-kB's +20us latency bomb);
//       tail = R3's ticket/amLast deterministic reduce (kills k4 launch).
// WINDOW=512, HOP=128, F=257, n_frames=(L-512)/128+1 (=1247 for L=160000).

#define FBINS 257

// table layout inside ws (floats)
#define TAB_BARK   0
#define TAB_ATHDB  257
#define TAB_ATHP   514
#define TAB_HANN   771
#define TAB_TWR    1283
#define TAB_TWI    1539
#define TAB_PSDMAX 1800   // uint, order-encoded float
#define TAB_CNTD   1803   // uint ticket counter
#define TAB_FLOATS 2048

// order-preserving float<->uint encoding (monotone)
__device__ inline unsigned enc_f(float f) {
    unsigned u = __float_as_uint(f);
    return (u & 0x80000000u) ? ~u : (u | 0x80000000u);
}
__device__ inline float dec_f(unsigned k) {
    return (k & 0x80000000u) ? __uint_as_float(k & 0x7fffffffu)
                             : __uint_as_float(~k);
}
__device__ inline float rl_f(float v, int l) {
    return __int_as_float(__builtin_amdgcn_readlane(__float_as_int(v), l));
}

// ---------------------------------------------------------------- kernel 0
__global__ __launch_bounds__(256) void k0_init(float* __restrict__ tab)
{
    const int tid = threadIdx.x;
    const double TWO_PI = 6.283185307179586476925286766559;
    for (int f = tid; f < FBINS; f += 256) {
        double freq = 31.25 * (double)f;            // SR/2/256 * f, exact
        double q    = freq / 7500.0;
        tab[TAB_BARK + f] = (float)(13.0 * atan(0.00076 * freq) + 3.5 * atan(q * q));
        if (f == 0) {
            tab[TAB_ATHDB] = -INFINITY;
            tab[TAB_ATHP]  = 0.0f;
        } else {
            double fk = freq * 0.001;
            double ad = 3.64 * pow(fk, -0.8)
                      - 6.5 * exp(-0.6 * (fk - 3.3) * (fk - 3.3))
                      + 0.001 * fk * fk * fk * fk - 12.0;
            float av = (float)ad;
            tab[TAB_ATHDB + f] = av;
            tab[TAB_ATHP  + f] = exp10f(av / 10.0f);
        }
    }
    for (int n = tid; n < 512; n += 256) {
        double cw = cos((TWO_PI * (double)n) / 512.0);
        tab[TAB_HANN + n] = (float)(0.5 * (1.0 - cw));
    }
    if (tid < 256) {
        double s, c;
        sincos(-(TWO_PI / 512.0) * (double)tid, &s, &c);
        tab[TAB_TWR + tid] = (float)c;
        tab[TAB_TWI + tid] = (float)s;
    }
    if (tid == 0) {
        ((unsigned*)tab)[TAB_PSDMAX] = 0u;   // < enc of any value >= -200
        ((unsigned*)tab)[TAB_CNTD]   = 0u;
    }
}

// ---------------------------------------------------------------- kernel 1
// R2's k1 body exact; final frame-max goes to device atomicMax (R3 seam).
__global__ __launch_bounds__(256) void k1_stft(
    const float* __restrict__ xadv, const float* __restrict__ xref,
    const float* __restrict__ tab,
    float* __restrict__ psd_db, float* __restrict__ pd,
    unsigned* __restrict__ psdmax_u)
{
    __shared__ float re[512], im[512], twr[256], twi[256];
    __shared__ float wmax[4];
    const int t = blockIdx.x, tid = threadIdx.x;

    twr[tid] = tab[TAB_TWR + tid];
    twi[tid] = tab[TAB_TWI + tid];

    const int base_idx = t * 128;
    for (int n = tid; n < 512; n += 256) {
        float w = tab[TAB_HANN + n];
        float r = xref[base_idx + n];
        float a = xadv[base_idx + n];
        int   p = __brev((unsigned)n) >> 23;   // 9-bit reversal
        re[p] = w * r;
        im[p] = w * (a - r);
    }
    __syncthreads();

    // 9-stage radix-2 DIT, one butterfly per thread per stage (R2 exact)
    for (int stage = 1; stage <= 9; ++stage) {
        int half  = 1 << (stage - 1);
        int tstep = 512 >> stage;
        int j     = tid & (half - 1);
        int base  = ((tid >> (stage - 1)) << stage) + j;
        float wr = twr[j * tstep], wi = twi[j * tstep];
        float vr0 = re[base + half], vi0 = im[base + half];
        float vr = vr0 * wr - vi0 * wi;
        float vi = vr0 * wi + vi0 * wr;
        float ur = re[base], ui = im[base];
        __syncthreads();   // reads done before writes of this stage
        re[base]        = ur + vr; im[base]        = ui + vi;
        re[base + half] = ur - vr; im[base + half] = ui - vi;
        __syncthreads();
    }

    // unpack A=rfft(ref), B=rfft(delta); PSDs (R2 exact)
    const float S2 = 1.0172526041666667e-05f;   // (sqrt(8/3)/512)^2
    float lmax = -1e30f;
    for (int k = tid; k <= 256; k += 256) {
        int nk = (512 - k) & 511;
        float zr = re[k],  zi = im[k];
        float yr = re[nk], yi = im[nk];
        float ar = 0.5f * (zr + yr), ai = 0.5f * (zi - yi);   // ref spectrum
        float br = 0.5f * (zi + yi), bi = 0.5f * (yr - zr);   // delta spectrum
        float prefp = S2 * (ar * ar + ai * ai);
        float pdb   = fmaxf(10.0f * log10f(prefp), -200.0f);
        psd_db[t * FBINS + k] = pdb;
        pd[t * FBINS + k]     = S2 * (br * br + bi * bi);
        lmax = fmaxf(lmax, pdb);
    }
    for (int off = 32; off > 0; off >>= 1) lmax = fmaxf(lmax, __shfl_down(lmax, off));
    if ((tid & 63) == 0) wmax[tid >> 6] = lmax;
    __syncthreads();
    if (tid == 0) {
        float m = fmaxf(fmaxf(wmax[0], wmax[1]), fmaxf(wmax[2], wmax[3]));
        atomicMax(psdmax_u, enc_f(m));          // R3-passed seam
    }
}

// ---------------------------------------------------------------- kernel 3
// R2's k3 body exact (block-per-frame); scan via readlane regs (R3-passed
// mechanism, same f32 compares); tail = R3's ticket/amLast reduce.
__global__ __launch_bounds__(256) void k3_threshold(
    const float* __restrict__ tab,
    const float* __restrict__ psd_db, const float* __restrict__ pd,
    const unsigned* __restrict__ psdmax_u, unsigned* __restrict__ counter,
    float* __restrict__ floss, float* __restrict__ out, int nf)
{
    __shared__ float barkf[FBINS], athp_s[FBINS];
    __shared__ float p_s[FBINS], pw_s[FBINS];
    __shared__ float mc_s[128], shift_s[128], barkm_s[128], ups_s[128];
    __shared__ int   bin_s[128], keep_s[128];
    __shared__ int   wcnt[4];
    __shared__ float red[4];
    __shared__ int   amLast;

    const int t = blockIdx.x, tid = threadIdx.x;
    const int lane = tid & 63, wid = tid >> 6;
    const float pmax   = dec_f(psdmax_u[0]);    // R3-passed seam
    const float shift0 = 96.0f - pmax;

    // tables + frame PSD into LDS (R2 exact)
    for (int f = tid; f < FBINS; f += 256) {
        barkf[f]  = tab[TAB_BARK + f];
        athp_s[f] = tab[TAB_ATHP + f];
        float pv = shift0 + psd_db[t * FBINS + f];
        p_s[f]  = pv;
        pw_s[f] = exp10f(pv / 10.0f);
    }
    __syncthreads();

    // local-max + tonal masker level for f = tid (R2 exact)
    float m = -1e30f;
    int   pred = 0;
    if (tid >= 1 && tid <= 255) {
        float pc = p_s[tid];
        if (pc > p_s[tid - 1] && pc > p_s[tid + 1]) {
            m = 10.0f * log10f((pw_s[tid] + pw_s[tid - 1]) + pw_s[tid + 1]);
            if (m > tab[TAB_ATHDB + tid]) pred = 1;
        }
    }
    // ballot stream-compaction (R2 exact)
    unsigned long long bal = __ballot(pred);
    if (lane == 0) wcnt[wid] = __popcll(bal);
    __syncthreads();
    int base = 0;
    for (int w = 0; w < wid; ++w) base += wcnt[w];
    const int n_total = wcnt[0] + wcnt[1] + wcnt[2] + wcnt[3];
    if (pred) {
        int pos = base + __popcll(bal & ((1ull << lane) - 1));
        bin_s[pos] = tid; mc_s[pos] = m; keep_s[pos] = 1;
    }
    __syncthreads();

    // lane-resident copies for the scan (wave 0): positions l and l+64
    float mcw0 = 0.0f, mcw1 = 0.0f, bkw0 = 0.0f, bkw1 = 0.0f;
    if (wid == 0) {
        mcw0 = mc_s[lane];      mcw1 = mc_s[lane + 64];
        bkw0 = barkf[lane];     bkw1 = barkf[lane + 64];
    }
    // sequential i_prev scan (R2's exact compare semantics incl. the
    // position-indexed BARK[] access); reads via readlane, keeps to LDS
    if (tid == 0 && n_total > 1) {
        int   i_prev = 0;
        float mcp = rl_f(mcw0, 0);
        float bkp = rl_f(bkw0, 0);
        for (int i = 1; i < n_total; ++i) {
            float mci = (i < 64) ? rl_f(mcw0, i) : rl_f(mcw1, i - 64);
            float bki = (i < 64) ? rl_f(bkw0, i) : rl_f(bkw1, i - 64);
            bool close        = (bki - bkp) < 0.5f;   // == barkf[i]-barkf[i_prev]
            bool prev_smaller = mcp < mci;
            if (close) {
                keep_s[prev_smaller ? i_prev : i] = 0;
                if (prev_smaller) {
                    i_prev += 1;
                    mcp = (i_prev < 64) ? rl_f(mcw0, i_prev) : rl_f(mcw1, i_prev - 64);
                    bkp = (i_prev < 64) ? rl_f(bkw0, i_prev) : rl_f(bkw1, i_prev - 64);
                }
            } else {
                i_prev = i;
                mcp = mci;
                bkp = bki;
            }
        }
    }
    __syncthreads();

    // compact kept maskers, precompute per-masker terms (R2 exact)
    int pred2 = (tid < n_total) && keep_s[tid];
    unsigned long long bal2 = __ballot(pred2);
    if (lane == 0) wcnt[wid] = __popcll(bal2);
    __syncthreads();
    int base2 = 0;
    for (int w = 0; w < wid; ++w) base2 += wcnt[w];
    const int nk = wcnt[0] + wcnt[1] + wcnt[2] + wcnt[3];
    if (pred2) {
        int pos = base2 + __popcll(bal2 & ((1ull << lane) - 1));
        int   fb = bin_s[tid];
        float mc = mc_s[tid];
        shift_s[pos] = mc + (-6.025f - 0.275f * barkf[fb]);
        barkm_s[pos] = barkf[fb];
        ups_s[pos]   = -27.0f + 0.37f * fmaxf(mc - 40.0f, 0.0f);
    }
    __syncthreads();

    // per-bin threshold power + loss (R2 exact; POWER domain)
    const float C = 3981071705.534973f / exp10f(pmax / 10.0f);  // 10^9.6/10^(pmax/10)
    float lsum = 0.0f;
    for (int f = tid; f < FBINS; f += 256) {
        float bf  = barkf[f];
        float acc = 0.0f;
        for (int k = 0; k < nk; ++k) {
            float dz    = bf - barkm_s[k];
            float slope = (dz > 0.0f) ? ups_s[k] : 27.0f;
            float tdb   = shift_s[k] + slope * dz;
            acc += exp10f(tdb / 10.0f);
        }
        float thrpow = acc + athp_s[f];
        float pds    = C * pd[t * FBINS + f];
        lsum += fmaxf(pds - thrpow, 0.0f);
    }
    for (int off = 32; off > 0; off >>= 1) lsum += __shfl_down(lsum, off);
    if ((tid & 63) == 0) red[tid >> 6] = lsum;
    __syncthreads();
    if (tid == 0) {
        floss[t] = (red[0] + red[1]) + (red[2] + red[3]);
        __threadfence();
        unsigned old = atomicAdd(counter, 1u);
        amLast = (old == (unsigned)(gridDim.x - 1));
    }
    __syncthreads();

    // last block: deterministic final mean (R3-passed tail; same sum shape as k4)
    if (amLast) {
        __threadfence();
        float s = 0.0f;
        for (int i = tid; i < nf; i += 256) s += floss[i];
        for (int off = 32; off > 0; off >>= 1) s += __shfl_down(s, off);
        if ((tid & 63) == 0) red[tid >> 6] = s;
        __syncthreads();
        if (tid == 0) {
            float total = (red[0] + red[1]) + (red[2] + red[3]);
            out[0] = 1e-6f * (total / (float)(nf * FBINS));
        }
    }
}

// ---------------------------------------------------------------- launch
extern "C" void kernel_launch(void* const* d_in, const int* in_sizes, int n_in,
                              void* d_out, int out_size, void* d_ws, size_t ws_size,
                              hipStream_t stream)
{
    const float* x_adv = (const float*)d_in[0];
    const float* x_ref = (const float*)d_in[1];
    float*       out   = (float*)d_out;

    const int L  = in_sizes[0];
    const int nf = (L - 512) / 128 + 1;           // 1247 for L=160000

    float* ws      = (float*)d_ws;
    float* tab     = ws;                                   // TAB_FLOATS
    float* psd_db  = ws + TAB_FLOATS;                      // nf*257
    float* pd      = psd_db + (size_t)nf * FBINS;          // nf*257
    float* floss   = pd + (size_t)nf * FBINS;              // nf
    unsigned* psdmax_u = (unsigned*)tab + TAB_PSDMAX;
    unsigned* counter  = (unsigned*)tab + TAB_CNTD;

    k0_init     <<<1,  256, 0, stream>>>(tab);
    k1_stft     <<<nf, 256, 0, stream>>>(x_adv, x_ref, tab, psd_db, pd, psdmax_u);
    k3_threshold<<<nf, 256, 0, stream>>>(tab, psd_db, pd, psdmax_u, counter,
                                         floss, out, nf);
}